// Round 3
// 4814.915 us; speedup vs baseline: 1.2150x; 1.2150x over previous
//
#include <hip/hip_runtime.h>
#include <cmath>

// ---------------------------------------------------------------------------
// Liquid NN (CfC) persistent-kernel implementation, R6 (resubmit — R2 bench
// was a GPUAcquisitionTimeout, kernel never ran).
//
// 32 groups x 8 WGs = 256 WGs (1/CU). Group owns 8 batch rows; WG owns 32
// units across the 3 layers -> 128 GEMM cols. Layer-skewed pipeline: tick k
// computes h0(k), h1(k-1), h2(k-2); one group barrier per tick.
// R6 vs R5 (R5 failed absmax 0.102; staging->reload chain and selective
// butterfly were the unauditable pieces -> both removed):
//  - weights gathered DIRECTLY global->VGPR per thread (k->src remap applied
//    element-wise at gather; correct by construction). No LDS weight staging.
//  - GEMM: 8 rows x 2 cols x 68-float K-chunk per thread (64 col-pairs x
//    4 chunk-lanes), z-only LDS reads: 4 distinct broadcast addrs per wave
//    instr, conflict-free (q-offsets at banks {0,4,8,12}).
//  - reduce: full all-reduce over 4 chunk-lanes (2x shfl_xor per value),
//    static ternary extraction of rows (2q, 2q+1). Trivially correct.
//  - f2-packed FMA accumulation (v_pk_fma_f32 candidate), fold at end.
//  - LDS = z buffers only: 3 x 8 x 272 = 26 KB.
// ---------------------------------------------------------------------------

constexpr int TT   = 1024;
constexpr int NB   = 256;
constexpr int GRP  = 32;     // groups (8 batch rows each)
constexpr int WPG  = 8;      // WGs per group
constexpr int CAT0 = 263, CAT1 = 224, CAT2 = 121;
constexpr int U0P = 136, U1P = 92, U2P = 32;

// uniform padded K: 4 chunks x 68 floats; z-row stride for all 3 layers
constexpr int ZP   = 272;
constexpr int CH   = 68;
constexpr int ZB0s = 0;
constexpr int ZB1s = 8 * ZP;        // 2176
constexpr int ZB2s = 16 * ZP;       // 4352
constexpr int ZTOT = 24 * ZP;       // 6528 dwords
constexpr int SMEM_BYTES = ZTOT * 4;        // 26112

// exchange block per (parity,group): [h0 8x136 | h1 8x92 | h2 8x32]
constexpr int HBLK   = 8*U0P + 8*U1P + 8*U2P;   // 2080 floats = 520 f4
constexpr int SEG1   = 8*U0P;                    // 1088
constexpr int SEG2   = SEG1 + 8*U1P;             // 1824
constexpr int FLAG_OFF = 2 * GRP * HBLK;         // 133120 dwords
constexpr int WS_DW    = FLAG_OFF + GRP * 16;    // 133632

typedef float f2 __attribute__((ext_vector_type(2)));

struct Params {
  const float* x;
  const float* w[3][4];
  const float* b[3][4];
  const int*   mk[3];
  float* hx;
  int*   flags;
  float* out;
};

__device__ __forceinline__ void sysstore(float* p, float v) {
  __hip_atomic_store(p, v, __ATOMIC_RELAXED, __HIP_MEMORY_SCOPE_SYSTEM);
}
// coherent (MALL-snooping) float4 load; value NOT ready until cwait()
__device__ __forceinline__ float4 cload(const float4* p) {
  float4 v;
  asm volatile("global_load_dwordx4 %0, %1, off sc0 sc1"
               : "=v"(v) : "v"(p) : "memory");
  return v;
}
__device__ __forceinline__ void cwait() {
  asm volatile("s_waitcnt vmcnt(0)" ::: "memory");
}
__device__ __forceinline__ float frcp(float x) { return __builtin_amdgcn_rcpf(x); }
__device__ __forceinline__ float ftanh(float x) {
  const float e = __expf(-2.f * fabsf(x));
  return copysignf((1.f - e) * frcp(1.f + e), x);
}

extern "C" __global__ void __launch_bounds__(256, 1)
lnn_main(Params p) {
  extern __shared__ float smem[];
  const int tid   = threadIdx.x;
  const int g     = blockIdx.x & 31;   // stride-32 peers share an XCD (heuristic)
  const int w_idx = blockIdx.x >> 5;   // 0..7 within group

  // ---- per-WG unit slices: WG0-6 get (17,11,4), WG7 gets (16,12,4) ---------
  const int n0  = (w_idx < 7) ? 17 : 16;
  const int us0 = w_idx * 17;
  const int n1  = (w_idx < 7) ? 11 : 12;
  const int us1 = w_idx * 11;
  const int us2 = w_idx * 4;

  // ---- per-thread GEMM mapping: 64 col-pairs x 4 K-chunk lanes -------------
  const int cp   = tid >> 2;          // col-pair 0..63 (cols 2cp, 2cp+1)
  const int q    = tid & 3;           // K-chunk lane
  const int tsel = cp & 1;            // 0: (ff1,ff2)  1: (ta,tb)
  const int s    = cp >> 1;           // unit slot 0..31
  int lyr, u_loc;
  if (s < n0)           { lyr = 0; u_loc = s; }
  else if (s < n0 + n1) { lyr = 1; u_loc = s - n0; }
  else                  { lyr = 2; u_loc = s - n0 - n1; }
  const int ug  = (lyr == 0) ? us0 + u_loc : (lyr == 1) ? us1 + u_loc : us2 + u_loc;
  const int cat = (lyr == 0) ? CAT0 : (lyr == 1) ? CAT1 : CAT2;
  const int zb  = (lyr == 0) ? ZB0s : (lyr == 1) ? ZB1s : ZB2s;
  const int seg = (lyr == 0) ? 0 : (lyr == 1) ? SEG1 : SEG2;
  const int UP  = (lyr == 0) ? U0P : (lyr == 1) ? U1P : U2P;
  const int zoff = zb + q * CH;
  const int b0 = q & 1, b1 = (q >> 1) & 1;
  const int rA = 2 * q;               // this chunk-lane owns rows (2q, 2q+1)

  // ---- weights: direct global -> VGPR gather (remap + mask, by construction)
  f2 wAl[17], wAh[17], wBl[17], wBh[17];
  {
    const float* gwA = p.w[lyr][tsel * 2]     + (size_t)ug * cat;
    const float* gwB = p.w[lyr][tsel * 2 + 1] + (size_t)ug * cat;
    const int*   gmk = p.mk[lyr]              + (size_t)ug * cat;
    const int k0 = q * CH;
    #pragma unroll
    for (int i = 0; i < 17; ++i) {
      float va[4], vb[4];
      #pragma unroll
      for (int e = 0; e < 4; ++e) {
        const int k = k0 + i * 4 + e;
        int src;
        if (lyr == 0)      src = (k < 263) ? k : -1;
        else if (lyr == 1) src = (k < 135) ? k : (k >= 136 && k < 225) ? k - 1 : -1;
        else               src = (k < 89)  ? k : (k >= 92  && k < 124) ? k - 3 : -1;
        float a = 0.f, b = 0.f;
        if (src >= 0) {
          a = gwA[src]; b = gwB[src];
          if (tsel == 0) { const float mm = (float)gmk[src]; a *= mm; b *= mm; }
        }
        va[e] = a; vb[e] = b;
      }
      wAl[i] = (f2){va[0], va[1]}; wAh[i] = (f2){va[2], va[3]};
      wBl[i] = (f2){vb[0], vb[1]}; wBh[i] = (f2){vb[2], vb[3]};
    }
  }
  const float bias0 = p.b[lyr][tsel * 2][ug];
  const float bias1 = p.b[lyr][tsel * 2 + 1][ug];

  // ---- zero z buffers once (pads stay zero forever) ------------------------
  for (int i = tid; i < ZTOT; i += 256) smem[i] = 0.f;
  __syncthreads();

  // ---- tick loop: k = 0 .. TT+2 (A@k, B@k-1, C@k-2, out-copy@k-3) ----------
  for (int k = 0; k < TT + 3; ++k) {
    const int p0 = (k - 1) & 1;   // parity holding h0(k-1) / h2(k-3)
    const int p1 = k & 1;         // parity holding h1(k-2)

    // -- coherent h loads: f4 idx [0,272)=h0@p0, [272,456)=h1@p1, [456,520)=h2@p0
    const float4* hx0 = (const float4*)(p.hx + (size_t)(p0 * GRP + g) * HBLK);
    const float4* hx1 = (const float4*)(p.hx + (size_t)(p1 * GRP + g) * HBLK);
    const int i1 = tid + 256;
    const float4 hv0 = cload(hx0 + tid);   // tid<256 -> always h0 region
    const float4 hv1 = cload((i1 >= 272 && i1 < 456) ? hx1 + i1 : hx0 + i1);
    float4 hvt;
    if (tid < 8) hvt = cload(hx0 + 512 + tid);

    // -- x copy (plain loads) --
    const int tx = (k < TT) ? k : TT - 1;
    {
      const int r = tid >> 5, c4 = (tid & 31) * 4;
      const float4 v = *(const float4*)(p.x + ((size_t)(g * 8 + r) * TT + tx) * 128 + c4);
      *(float4*)(&smem[r * ZP + c4]) = v;
    }

    cwait();

    // -- scatter h to LDS (dual stores for shared segments) --
    {
      const int r = tid / 34, c4 = (tid - r * 34) * 4;   // h0 part
      *(float4*)(&smem[r * ZP + 128 + c4]) = hv0;
      *(float4*)(&smem[ZB1s + r * ZP + c4]) = hv0;
    }
    if (i1 < 272) {
      const int r = i1 / 34, c4 = (i1 - r * 34) * 4;
      *(float4*)(&smem[r * ZP + 128 + c4]) = hv1;
      *(float4*)(&smem[ZB1s + r * ZP + c4]) = hv1;
    } else if (i1 < 456) {
      const int j = i1 - 272;
      const int r = j / 23, c4 = (j - r * 23) * 4;
      *(float4*)(&smem[ZB1s + r * ZP + 136 + c4]) = hv1;
      *(float4*)(&smem[ZB2s + r * ZP + c4]) = hv1;
    } else {
      const int j = i1 - 456;
      const int r = j >> 3, c4 = (j & 7) * 4;
      *(float4*)(&smem[ZB2s + r * ZP + 92 + c4]) = hv1;
    }
    if (tid < 8) {
      const int j = tid + 56;                            // f4 idx 512..519
      const int r = j >> 3, c4 = (j & 7) * 4;
      *(float4*)(&smem[ZB2s + r * ZP + 92 + c4]) = hvt;
    }
    __syncthreads();

    // -- coalesced out write: h2(k-3) assembled in z2; WG w owns row w --
    if (tid < 8 && k >= 3) {
      const float4 v = *(const float4*)(&smem[ZB2s + w_idx * ZP + 92 + tid * 4]);
      *(float4*)(&p.out[((size_t)(g * 8 + w_idx) * TT + (k - 3)) * 32 + tid * 4]) = v;
    }

    // -- fused GEMM: 8 rows x 2 cols x this lane's 68-float K-chunk --
    f2 accA[8], accB[8];
    #pragma unroll
    for (int r = 0; r < 8; ++r) { accA[r] = (f2){0.f, 0.f}; accB[r] = (f2){0.f, 0.f}; }
    {
      const float* zp = &smem[zoff];
      #pragma unroll
      for (int i = 0; i < 17; ++i) {
        #pragma unroll
        for (int r = 0; r < 8; ++r) {
          const float4 a = *(const float4*)(zp + r * ZP + i * 4);
          const f2 al = {a.x, a.y}, ah = {a.z, a.w};
          accA[r] = __builtin_elementwise_fma(al, wAl[i], accA[r]);
          accB[r] = __builtin_elementwise_fma(al, wBl[i], accB[r]);
          accA[r] = __builtin_elementwise_fma(ah, wAh[i], accA[r]);
          accB[r] = __builtin_elementwise_fma(ah, wBh[i], accB[r]);
        }
      }
    }

    // -- full all-reduce over the 4 chunk-lanes (every lane gets all 8 rows) --
    float acc[8][2];
    #pragma unroll
    for (int r = 0; r < 8; ++r) {
      float u0 = accA[r].x + accA[r].y;
      float u1 = accB[r].x + accB[r].y;
      u0 += __shfl_xor(u0, 1);  u0 += __shfl_xor(u0, 2);
      u1 += __shfl_xor(u1, 1);  u1 += __shfl_xor(u1, 2);
      acc[r][0] = u0; acc[r][1] = u1;
    }

    // -- static extraction of this lane's rows (2q, 2q+1) --
    const float v00 = (b1 ? (b0 ? acc[6][0] : acc[4][0]) : (b0 ? acc[2][0] : acc[0][0])) + bias0;
    const float v01 = (b1 ? (b0 ? acc[6][1] : acc[4][1]) : (b0 ? acc[2][1] : acc[0][1])) + bias1;
    const float v10 = (b1 ? (b0 ? acc[7][0] : acc[5][0]) : (b0 ? acc[3][0] : acc[1][0])) + bias0;
    const float v11 = (b1 ? (b0 ? acc[7][1] : acc[5][1]) : (b0 ? acc[3][1] : acc[1][1])) + bias1;

    // -- combine: ta/tb pair -> sigmoid, shfl (lane+4) to ff pair --
    float sA = v00 + v01, sB = v10 + v11;
    sA = frcp(1.f + __expf(-sA));
    sB = frcp(1.f + __expf(-sB));
    const float gA = __shfl_down(sA, 4);
    const float gB = __shfl_down(sB, 4);
    if (tsel == 0) {
      const float hA = ftanh(v00) * (1.f - gA) + gA * ftanh(v01);
      const float hB = ftanh(v10) * (1.f - gB) + gB * ftanh(v11);
      const int tl = k - lyr;
      if (tl >= 0 && tl < TT) {
        float* dst = p.hx + (size_t)((tl & 1) * GRP + g) * HBLK + seg + ug;
        sysstore(dst + (size_t)rA * UP, hA);            // write-through to MALL
        sysstore(dst + (size_t)(rA + 1) * UP, hB);
      }
    }

    // -- group barrier: per-WG flag store (no RMW) + 8-lane single-line poll --
    __syncthreads();   // all waves drain vmcnt (h stores acked at MALL)
    if (tid == 0)
      __hip_atomic_store(&p.flags[g * 16 + w_idx], k + 1,
                         __ATOMIC_RELAXED, __HIP_MEMORY_SCOPE_SYSTEM);
    if (k < TT + 2) {
      if (tid < WPG) {
        const int* fp = &p.flags[g * 16 + tid];
        while (__hip_atomic_load(fp, __ATOMIC_RELAXED, __HIP_MEMORY_SCOPE_SYSTEM) < k + 1)
          __builtin_amdgcn_s_sleep(1);
      }
      __syncthreads();
    }
  }
}

// in-place fc: out[b,t,:] = out[b,t,:] @ fc_w.T + fc_b  (pool is identity)
extern "C" __global__ void __launch_bounds__(256)
lnn_fc(float* out, const float* fcw, const float* fcb) {
  __shared__ float w[32 * 33];
  __shared__ float bb[32];
  __shared__ float tile[8 * 32];
  const int tid = threadIdx.x;
  for (int i = tid; i < 1024; i += 256) w[(i >> 5) * 33 + (i & 31)] = fcw[i];
  if (tid < 32) bb[tid] = fcb[tid];
  const size_t base = (size_t)blockIdx.x * 256;
  tile[tid] = out[base + tid];
  __syncthreads();
  const int pp = tid >> 5, o = tid & 31;
  float acc = bb[o];
  #pragma unroll
  for (int u = 0; u < 32; ++u) acc = fmaf(tile[pp * 32 + u], w[o * 33 + u], acc);
  out[base + pp * 32 + o] = acc;
}

extern "C" void kernel_launch(void* const* d_in, const int* in_sizes, int n_in,
                              void* d_out, int out_size, void* d_ws, size_t ws_size,
                              hipStream_t stream) {
  Params p;
  p.x = (const float*)d_in[0];
  const int wi[3] = {1, 10, 19};
  for (int l = 0; l < 3; ++l) {
    for (int m = 0; m < 4; ++m) {
      p.w[l][m] = (const float*)d_in[wi[l] + 2 * m];
      p.b[l][m] = (const float*)d_in[wi[l] + 2 * m + 1];
    }
  }
  p.mk[0] = (const int*)d_in[9];
  p.mk[1] = (const int*)d_in[18];
  p.mk[2] = (const int*)d_in[27];
  float* ws = (float*)d_ws;
  p.hx    = ws;
  p.flags = (int*)(ws + FLAG_OFF);
  p.out   = (float*)d_out;

  hipFuncSetAttribute(reinterpret_cast<const void*>(lnn_main),
                      hipFuncAttributeMaxDynamicSharedMemorySize, SMEM_BYTES);
  hipMemsetAsync(d_ws, 0, (size_t)WS_DW * 4, stream);
  lnn_main<<<dim3(GRP * WPG), dim3(256), SMEM_BYTES, stream>>>(p);
  lnn_fc<<<dim3(NB * TT / 8), dim3(256), 0, stream>>>(
      (float*)d_out, (const float*)d_in[28], (const float*)d_in[29]);
}

// Round 5
// 4511.700 us; speedup vs baseline: 1.2966x; 1.0672x over previous
//
#include <hip/hip_runtime.h>
#include <cmath>

// ---------------------------------------------------------------------------
// Liquid NN (CfC) persistent-kernel implementation, R8.
//
// 32 groups x 8 WGs = 256 WGs (1/CU). Group owns 8 batch rows; WG owns 32
// units across the 3 layers. Layer-skewed pipeline: tick k computes h0(k),
// h1(k-1), h2(k-2); one group barrier per tick.
// R8 vs R7 (failed) / R6 (passed, 4815us): keep R7's economics (one unit per
// 8-thread group, 8-way K-split -> 72 z-reads/thread), rebuild the reduce
// from ONLY R6-proven mechanics. Empirical rule from R5/R6/R7: selective
// (lane-dependent-operand) shuffle exchanges fail; symmetric allreduce +
// post-selection passes.
//  - ta/tb weights PRE-SUMMED at gather (only sigmoid(ta+tb) is ever used):
//    3 weight sets, 108 VGPRs, GEMM FMAs -25%, reduce values 4->3.
//  - contiguous 36-float K-chunks (k0 = q8*36), ZP=288. Banks: lane q8 ->
//    quad 4(q8+i) mod 32, 8 distinct quads -> conflict-free.
//  - per-row reduce: symmetric __shfl_xor(1)/(2) (proven transport) + compile-
//    time cndmask extraction (own row q8, give row q8^4).
//  - b2-half exchange via LDS scratch + __syncthreads (no selective shuffle,
//    no DPP). Combine fully thread-local.
// ---------------------------------------------------------------------------

constexpr int TT   = 1024;
constexpr int NB   = 256;
constexpr int GRP  = 32;     // groups (8 batch rows each)
constexpr int WPG  = 8;      // WGs per group
constexpr int CAT0 = 263, CAT1 = 224, CAT2 = 121;
constexpr int U0P = 136, U1P = 92, U2P = 32;

// uniform padded K: 8 lanes x 36 floats = 288; z-row stride for all layers
constexpr int ZP   = 288;
constexpr int ZB0s = 0;
constexpr int ZB1s = 8 * ZP;        // 2304
constexpr int ZB2s = 16 * ZP;       // 4608
constexpr int ZTOT = 24 * ZP;       // 6912 dwords
constexpr int SCR  = ZTOT;          // scratch: 256 threads x 4 dwords
constexpr int SMEM_DW    = ZTOT + 256 * 4;  // 7936
constexpr int SMEM_BYTES = SMEM_DW * 4;     // 31744

// exchange block per (parity,group): [h0 8x136 | h1 8x92 | h2 8x32]
constexpr int HBLK   = 8*U0P + 8*U1P + 8*U2P;   // 2080 floats = 520 f4
constexpr int SEG1   = 8*U0P;                    // 1088
constexpr int SEG2   = SEG1 + 8*U1P;             // 1824
constexpr int FLAG_OFF = 2 * GRP * HBLK;         // 133120 dwords
constexpr int WS_DW    = FLAG_OFF + GRP * 16;    // 133632

typedef float f2 __attribute__((ext_vector_type(2)));

struct Params {
  const float* x;
  const float* w[3][4];
  const float* b[3][4];
  const int*   mk[3];
  float* hx;
  int*   flags;
  float* out;
};

__device__ __forceinline__ void sysstore(float* p, float v) {
  __hip_atomic_store(p, v, __ATOMIC_RELAXED, __HIP_MEMORY_SCOPE_SYSTEM);
}
// coherent (MALL-snooping) float4 load; value NOT ready until cwait()
__device__ __forceinline__ float4 cload(const float4* p) {
  float4 v;
  asm volatile("global_load_dwordx4 %0, %1, off sc0 sc1"
               : "=v"(v) : "v"(p) : "memory");
  return v;
}
__device__ __forceinline__ void cwait() {
  asm volatile("s_waitcnt vmcnt(0)" ::: "memory");
}
__device__ __forceinline__ float frcp(float x) { return __builtin_amdgcn_rcpf(x); }
__device__ __forceinline__ float ftanh(float x) {
  const float e = __expf(-2.f * fabsf(x));
  return copysignf((1.f - e) * frcp(1.f + e), x);
}

extern "C" __global__ void __launch_bounds__(256, 1)
lnn_main(Params p) {
  extern __shared__ float smem[];
  const int tid   = threadIdx.x;
  const int g     = blockIdx.x & 31;   // stride-32 peers share an XCD (heuristic)
  const int w_idx = blockIdx.x >> 5;   // 0..7 within group

  // ---- per-WG unit slices: WG0-6 get (17,11,4), WG7 gets (16,12,4) ---------
  const int n0  = (w_idx < 7) ? 17 : 16;
  const int us0 = w_idx * 17;
  const int n1  = (w_idx < 7) ? 11 : 12;
  const int us1 = w_idx * 11;
  const int us2 = w_idx * 4;

  // ---- per-thread GEMM mapping: 32 units x 8 K-lanes ----------------------
  const int q8 = tid & 7;             // K-chunk lane; also final row owner
  const int s  = tid >> 3;            // unit slot 0..31
  int lyr, u_loc;
  if (s < n0)           { lyr = 0; u_loc = s; }
  else if (s < n0 + n1) { lyr = 1; u_loc = s - n0; }
  else                  { lyr = 2; u_loc = s - n0 - n1; }
  const int ug  = (lyr == 0) ? us0 + u_loc : (lyr == 1) ? us1 + u_loc : us2 + u_loc;
  const int cat = (lyr == 0) ? CAT0 : (lyr == 1) ? CAT1 : CAT2;
  const int zb  = (lyr == 0) ? ZB0s : (lyr == 1) ? ZB1s : ZB2s;
  const int seg = (lyr == 0) ? 0 : (lyr == 1) ? SEG1 : SEG2;
  const int UP  = (lyr == 0) ? U0P : (lyr == 1) ? U1P : U2P;
  const int k0  = q8 * 36;            // contiguous 36-float K-chunk

  // ---- weights: direct global -> VGPR gather (remap + mask, by construction)
  // 3 sets: w0 = ff1*mask, w1 = ff2*mask, w2 = ta + tb (pre-summed).
  f2 w0l[9], w0h[9], w1l[9], w1h[9], w2l[9], w2h[9];
  {
    const float* gw0 = p.w[lyr][0] + (size_t)ug * cat;
    const float* gw1 = p.w[lyr][1] + (size_t)ug * cat;
    const float* gw2 = p.w[lyr][2] + (size_t)ug * cat;
    const float* gw3 = p.w[lyr][3] + (size_t)ug * cat;
    const int*   gmk = p.mk[lyr]   + (size_t)ug * cat;
    #pragma unroll
    for (int i = 0; i < 9; ++i) {
      float v0[4], v1[4], v2[4];
      #pragma unroll
      for (int e = 0; e < 4; ++e) {
        const int k = k0 + i * 4 + e;
        int src;
        if (lyr == 0)      src = (k < 263) ? k : -1;
        else if (lyr == 1) src = (k < 135) ? k : (k >= 136 && k < 225) ? k - 1 : -1;
        else               src = (k < 89)  ? k : (k >= 92  && k < 124) ? k - 3 : -1;
        float a = 0.f, b = 0.f, c = 0.f;
        if (src >= 0) {
          const float mm = (float)gmk[src];      // mask applies to ff1/ff2 only
          a = gw0[src] * mm;
          b = gw1[src] * mm;
          c = gw2[src] + gw3[src];
        }
        v0[e] = a; v1[e] = b; v2[e] = c;
      }
      w0l[i] = (f2){v0[0], v0[1]}; w0h[i] = (f2){v0[2], v0[3]};
      w1l[i] = (f2){v1[0], v1[1]}; w1h[i] = (f2){v1[2], v1[3]};
      w2l[i] = (f2){v2[0], v2[1]}; w2h[i] = (f2){v2[2], v2[3]};
    }
  }
  const float bf1 = p.b[lyr][0][ug];
  const float bf2 = p.b[lyr][1][ug];
  const float bt  = p.b[lyr][2][ug] + p.b[lyr][3][ug];

  // ---- zero z buffers once (pads stay zero forever) ------------------------
  for (int i = tid; i < ZTOT; i += 256) smem[i] = 0.f;
  __syncthreads();

  // ---- tick loop: k = 0 .. TT+2 (A@k, B@k-1, C@k-2, out-copy@k-3) ----------
  for (int k = 0; k < TT + 3; ++k) {
    const int p0 = (k - 1) & 1;   // parity holding h0(k-1) / h2(k-3)
    const int p1 = k & 1;         // parity holding h1(k-2)

    // -- coherent h loads: f4 idx [0,272)=h0@p0, [272,456)=h1@p1, [456,520)=h2@p0
    const float4* hx0 = (const float4*)(p.hx + (size_t)(p0 * GRP + g) * HBLK);
    const float4* hx1 = (const float4*)(p.hx + (size_t)(p1 * GRP + g) * HBLK);
    const int i1 = tid + 256;
    const float4 hv0 = cload(hx0 + tid);   // tid<256 -> always h0 region
    const float4 hv1 = cload((i1 >= 272 && i1 < 456) ? hx1 + i1 : hx0 + i1);
    float4 hvt;
    if (tid < 8) hvt = cload(hx0 + 512 + tid);

    // -- x copy (plain loads) --
    const int tx = (k < TT) ? k : TT - 1;
    {
      const int r = tid >> 5, c4 = (tid & 31) * 4;
      const float4 v = *(const float4*)(p.x + ((size_t)(g * 8 + r) * TT + tx) * 128 + c4);
      *(float4*)(&smem[r * ZP + c4]) = v;
    }

    cwait();

    // -- scatter h to LDS (dual stores for shared segments) --
    {
      const int r = tid / 34, c4 = (tid - r * 34) * 4;   // h0 part
      *(float4*)(&smem[r * ZP + 128 + c4]) = hv0;
      *(float4*)(&smem[ZB1s + r * ZP + c4]) = hv0;
    }
    if (i1 < 272) {
      const int r = i1 / 34, c4 = (i1 - r * 34) * 4;
      *(float4*)(&smem[r * ZP + 128 + c4]) = hv1;
      *(float4*)(&smem[ZB1s + r * ZP + c4]) = hv1;
    } else if (i1 < 456) {
      const int j = i1 - 272;
      const int r = j / 23, c4 = (j - r * 23) * 4;
      *(float4*)(&smem[ZB1s + r * ZP + 136 + c4]) = hv1;
      *(float4*)(&smem[ZB2s + r * ZP + c4]) = hv1;
    } else {
      const int j = i1 - 456;
      const int r = j >> 3, c4 = (j & 7) * 4;
      *(float4*)(&smem[ZB2s + r * ZP + 92 + c4]) = hv1;
    }
    if (tid < 8) {
      const int j = tid + 56;                            // f4 idx 512..519
      const int r = j >> 3, c4 = (j & 7) * 4;
      *(float4*)(&smem[ZB2s + r * ZP + 92 + c4]) = hvt;
    }
    __syncthreads();

    // -- coalesced out write: h2(k-3) assembled in z2; WG w owns row w --
    if (tid < 8 && k >= 3) {
      const float4 v = *(const float4*)(&smem[ZB2s + w_idx * ZP + 92 + tid * 4]);
      *(float4*)(&p.out[((size_t)(g * 8 + w_idx) * TT + (k - 3)) * 32 + tid * 4]) = v;
    }

    // -- fused GEMM, per-row: 3 mats x 9 f4 chunk reads; symmetric reduce
    //    over K-lanes {b0,b1} via shfl_xor(1)/(2); compile-time extraction.
    float own0 = 0.f, own1 = 0.f, own2 = 0.f;
    float giv0 = 0.f, giv1 = 0.f, giv2 = 0.f;
    {
      const float* zp = &smem[zb + k0];
      #pragma unroll
      for (int r = 0; r < 8; ++r) {
        f2 a0 = {0.f, 0.f}, a1 = {0.f, 0.f}, a2 = {0.f, 0.f};
        #pragma unroll
        for (int i = 0; i < 9; ++i) {
          const float4 z4 = *(const float4*)(zp + r * ZP + i * 4);
          const f2 zl = {z4.x, z4.y}, zh = {z4.z, z4.w};
          a0 = __builtin_elementwise_fma(zl, w0l[i], a0);
          a1 = __builtin_elementwise_fma(zl, w1l[i], a1);
          a2 = __builtin_elementwise_fma(zl, w2l[i], a2);
          a0 = __builtin_elementwise_fma(zh, w0h[i], a0);
          a1 = __builtin_elementwise_fma(zh, w1h[i], a1);
          a2 = __builtin_elementwise_fma(zh, w2h[i], a2);
        }
        float u0 = a0.x + a0.y, u1 = a1.x + a1.y, u2 = a2.x + a2.y;
        u0 += __shfl_xor(u0, 1);  u0 += __shfl_xor(u0, 2);
        u1 += __shfl_xor(u1, 1);  u1 += __shfl_xor(u1, 2);
        u2 += __shfl_xor(u2, 1);  u2 += __shfl_xor(u2, 2);
        if (r == q8)       { own0 = u0; own1 = u1; own2 = u2; }
        if (r == (q8 ^ 4)) { giv0 = u0; giv1 = u1; giv2 = u2; }
      }
    }
    // -- cross-half exchange (b2 subgroups) via LDS scratch: lane writes its
    //    partner's row-partial; partner (tid^4, same wave) picks it up.
    *(float4*)(&smem[SCR + tid * 4]) = (float4){giv0, giv1, giv2, 0.f};
    __syncthreads();
    const float4 par = *(const float4*)(&smem[SCR + (tid ^ 4) * 4]);

    const float F1 = own0 + par.x + bf1;
    const float F2 = own1 + par.y + bf2;
    const float T  = own2 + par.z + bt;
    const float t  = frcp(1.f + __expf(-T));
    const float h  = ftanh(F1) * (1.f - t) + t * ftanh(F2);
    const int   tl = k - lyr;
    if (tl >= 0 && tl < TT) {
      float* dst = p.hx + (size_t)((tl & 1) * GRP + g) * HBLK + seg + ug;
      sysstore(dst + (size_t)q8 * UP, h);               // write-through to MALL
    }

    // -- group barrier: per-WG flag store (no RMW) + 8-lane single-line poll --
    __syncthreads();   // all waves drain vmcnt (h stores acked at MALL)
    if (tid == 0)
      __hip_atomic_store(&p.flags[g * 16 + w_idx], k + 1,
                         __ATOMIC_RELAXED, __HIP_MEMORY_SCOPE_SYSTEM);
    if (k < TT + 2) {
      if (tid < WPG) {
        const int* fp = &p.flags[g * 16 + tid];
        while (__hip_atomic_load(fp, __ATOMIC_RELAXED, __HIP_MEMORY_SCOPE_SYSTEM) < k + 1)
          __builtin_amdgcn_s_sleep(1);
      }
      __syncthreads();
    }
  }
}

// in-place fc: out[b,t,:] = out[b,t,:] @ fc_w.T + fc_b  (pool is identity)
extern "C" __global__ void __launch_bounds__(256)
lnn_fc(float* out, const float* fcw, const float* fcb) {
  __shared__ float w[32 * 33];
  __shared__ float bb[32];
  __shared__ float tile[8 * 32];
  const int tid = threadIdx.x;
  for (int i = tid; i < 1024; i += 256) w[(i >> 5) * 33 + (i & 31)] = fcw[i];
  if (tid < 32) bb[tid] = fcb[tid];
  const size_t base = (size_t)blockIdx.x * 256;
  tile[tid] = out[base + tid];
  __syncthreads();
  const int pp = tid >> 5, o = tid & 31;
  float acc = bb[o];
  #pragma unroll
  for (int u = 0; u < 32; ++u) acc = fmaf(tile[pp * 32 + u], w[o * 33 + u], acc);
  out[base + pp * 32 + o] = acc;
}

extern "C" void kernel_launch(void* const* d_in, const int* in_sizes, int n_in,
                              void* d_out, int out_size, void* d_ws, size_t ws_size,
                              hipStream_t stream) {
  Params p;
  p.x = (const float*)d_in[0];
  const int wi[3] = {1, 10, 19};
  for (int l = 0; l < 3; ++l) {
    for (int m = 0; m < 4; ++m) {
      p.w[l][m] = (const float*)d_in[wi[l] + 2 * m];
      p.b[l][m] = (const float*)d_in[wi[l] + 2 * m + 1];
    }
  }
  p.mk[0] = (const int*)d_in[9];
  p.mk[1] = (const int*)d_in[18];
  p.mk[2] = (const int*)d_in[27];
  float* ws = (float*)d_ws;
  p.hx    = ws;
  p.flags = (int*)(ws + FLAG_OFF);
  p.out   = (float*)d_out;

  hipFuncSetAttribute(reinterpret_cast<const void*>(lnn_main),
                      hipFuncAttributeMaxDynamicSharedMemorySize, SMEM_BYTES);
  hipMemsetAsync(d_ws, 0, (size_t)WS_DW * 4, stream);
  lnn_main<<<dim3(GRP * WPG), dim3(256), SMEM_BYTES, stream>>>(p);
  lnn_fc<<<dim3(NB * TT / 8), dim3(256), 0, stream>>>(
      (float*)d_out, (const float*)d_in[28], (const float*)d_in[29]);
}

// Round 7
// 4323.409 us; speedup vs baseline: 1.3531x; 1.0436x over previous
//
#include <hip/hip_runtime.h>
#include <cmath>

// ---------------------------------------------------------------------------
// Liquid NN (CfC) persistent-kernel implementation, R10.
//
// 32 groups x 8 WGs = 256 WGs (1/CU). Group owns 8 batch rows; WG owns 32
// units across the 3 layers. Layer-skewed pipeline: tick k computes h0(k),
// h1(k-1), h2(k-2); one group barrier per tick.
// R10 = exact R8 (4512us, passed) + two value-identical latency edits.
// Empirical rule R5-R9: rounds touching the h-exchange/scatter indexing
// failed; rounds keeping the R4-proven 8-row exchange verbatim passed.
// So: exchange kept byte-identical; only scheduling changed.
//  - x register prefetch: x(k+1) loaded during tick k's GEMM phase (it is
//    barrier-independent), stored to LDS at tick k+1 top. Takes the x global
//    load latency off the serial chain {poll -> cload h -> cwait -> scatter}.
//  - in-wave scratch exchange: partner tid^4 is same-wave, so the scratch
//    __syncthreads is replaced by s_waitcnt lgkmcnt(0) + sched_barrier(0)
//    (one fewer convergence point; waves drift and overlap).
// ---------------------------------------------------------------------------

constexpr int TT   = 1024;
constexpr int NB   = 256;
constexpr int GRP  = 32;     // groups (8 batch rows each)
constexpr int WPG  = 8;      // WGs per group
constexpr int CAT0 = 263, CAT1 = 224, CAT2 = 121;
constexpr int U0P = 136, U1P = 92, U2P = 32;

// uniform padded K: 8 lanes x 36 floats = 288; z-row stride for all layers
constexpr int ZP   = 288;
constexpr int ZB0s = 0;
constexpr int ZB1s = 8 * ZP;        // 2304
constexpr int ZB2s = 16 * ZP;       // 4608
constexpr int ZTOT = 24 * ZP;       // 6912 dwords
constexpr int SCR  = ZTOT;          // scratch: 256 threads x 4 dwords
constexpr int SMEM_DW    = ZTOT + 256 * 4;  // 7936
constexpr int SMEM_BYTES = SMEM_DW * 4;     // 31744

// exchange block per (parity,group): [h0 8x136 | h1 8x92 | h2 8x32]
constexpr int HBLK   = 8*U0P + 8*U1P + 8*U2P;   // 2080 floats = 520 f4
constexpr int SEG1   = 8*U0P;                    // 1088
constexpr int SEG2   = SEG1 + 8*U1P;             // 1824
constexpr int FLAG_OFF = 2 * GRP * HBLK;         // 133120 dwords
constexpr int WS_DW    = FLAG_OFF + GRP * 16;    // 133632

typedef float f2 __attribute__((ext_vector_type(2)));

struct Params {
  const float* x;
  const float* w[3][4];
  const float* b[3][4];
  const int*   mk[3];
  float* hx;
  int*   flags;
  float* out;
};

__device__ __forceinline__ void sysstore(float* p, float v) {
  __hip_atomic_store(p, v, __ATOMIC_RELAXED, __HIP_MEMORY_SCOPE_SYSTEM);
}
// coherent (MALL-snooping) float4 load; value NOT ready until cwait()
__device__ __forceinline__ float4 cload(const float4* p) {
  float4 v;
  asm volatile("global_load_dwordx4 %0, %1, off sc0 sc1"
               : "=v"(v) : "v"(p) : "memory");
  return v;
}
__device__ __forceinline__ void cwait() {
  asm volatile("s_waitcnt vmcnt(0)" ::: "memory");
}
__device__ __forceinline__ float frcp(float x) { return __builtin_amdgcn_rcpf(x); }
__device__ __forceinline__ float ftanh(float x) {
  const float e = __expf(-2.f * fabsf(x));
  return copysignf((1.f - e) * frcp(1.f + e), x);
}

extern "C" __global__ void __launch_bounds__(256, 1)
lnn_main(Params p) {
  extern __shared__ float smem[];
  const int tid   = threadIdx.x;
  const int g     = blockIdx.x & 31;   // stride-32 peers share an XCD (heuristic)
  const int w_idx = blockIdx.x >> 5;   // 0..7 within group

  // ---- per-WG unit slices: WG0-6 get (17,11,4), WG7 gets (16,12,4) ---------
  const int n0  = (w_idx < 7) ? 17 : 16;
  const int us0 = w_idx * 17;
  const int n1  = (w_idx < 7) ? 11 : 12;
  const int us1 = w_idx * 11;
  const int us2 = w_idx * 4;

  // ---- per-thread GEMM mapping: 32 units x 8 K-lanes ----------------------
  const int q8 = tid & 7;             // K-chunk lane; also final row owner
  const int s  = tid >> 3;            // unit slot 0..31
  int lyr, u_loc;
  if (s < n0)           { lyr = 0; u_loc = s; }
  else if (s < n0 + n1) { lyr = 1; u_loc = s - n0; }
  else                  { lyr = 2; u_loc = s - n0 - n1; }
  const int ug  = (lyr == 0) ? us0 + u_loc : (lyr == 1) ? us1 + u_loc : us2 + u_loc;
  const int cat = (lyr == 0) ? CAT0 : (lyr == 1) ? CAT1 : CAT2;
  const int zb  = (lyr == 0) ? ZB0s : (lyr == 1) ? ZB1s : ZB2s;
  const int seg = (lyr == 0) ? 0 : (lyr == 1) ? SEG1 : SEG2;
  const int UP  = (lyr == 0) ? U0P : (lyr == 1) ? U1P : U2P;
  const int k0  = q8 * 36;            // contiguous 36-float K-chunk

  // ---- weights: direct global -> VGPR gather (remap + mask, by construction)
  // 3 sets: w0 = ff1*mask, w1 = ff2*mask, w2 = ta + tb (pre-summed).
  f2 w0l[9], w0h[9], w1l[9], w1h[9], w2l[9], w2h[9];
  {
    const float* gw0 = p.w[lyr][0] + (size_t)ug * cat;
    const float* gw1 = p.w[lyr][1] + (size_t)ug * cat;
    const float* gw2 = p.w[lyr][2] + (size_t)ug * cat;
    const float* gw3 = p.w[lyr][3] + (size_t)ug * cat;
    const int*   gmk = p.mk[lyr]   + (size_t)ug * cat;
    #pragma unroll
    for (int i = 0; i < 9; ++i) {
      float v0[4], v1[4], v2[4];
      #pragma unroll
      for (int e = 0; e < 4; ++e) {
        const int k = k0 + i * 4 + e;
        int src;
        if (lyr == 0)      src = (k < 263) ? k : -1;
        else if (lyr == 1) src = (k < 135) ? k : (k >= 136 && k < 225) ? k - 1 : -1;
        else               src = (k < 89)  ? k : (k >= 92  && k < 124) ? k - 3 : -1;
        float a = 0.f, b = 0.f, c = 0.f;
        if (src >= 0) {
          const float mm = (float)gmk[src];      // mask applies to ff1/ff2 only
          a = gw0[src] * mm;
          b = gw1[src] * mm;
          c = gw2[src] + gw3[src];
        }
        v0[e] = a; v1[e] = b; v2[e] = c;
      }
      w0l[i] = (f2){v0[0], v0[1]}; w0h[i] = (f2){v0[2], v0[3]};
      w1l[i] = (f2){v1[0], v1[1]}; w1h[i] = (f2){v1[2], v1[3]};
      w2l[i] = (f2){v2[0], v2[1]}; w2h[i] = (f2){v2[2], v2[3]};
    }
  }
  const float bf1 = p.b[lyr][0][ug];
  const float bf2 = p.b[lyr][1][ug];
  const float bt  = p.b[lyr][2][ug] + p.b[lyr][3][ug];

  // ---- zero z buffers once (pads stay zero forever) ------------------------
  for (int i = tid; i < ZTOT; i += 256) smem[i] = 0.f;
  __syncthreads();

  // ---- x register prefetch (barrier-independent path) ----------------------
  const int xr_r = tid >> 5, xr_c4 = (tid & 31) * 4;
  const float* xbase = p.x + ((size_t)(g * 8 + xr_r) * TT) * 128 + xr_c4;
  float4 xr = *(const float4*)(xbase);   // t = 0

  // ---- tick loop: k = 0 .. TT+2 (A@k, B@k-1, C@k-2, out-copy@k-3) ----------
  for (int k = 0; k < TT + 3; ++k) {
    const int p0 = (k - 1) & 1;   // parity holding h0(k-1) / h2(k-3)
    const int p1 = k & 1;         // parity holding h1(k-2)

    // -- coherent h loads: f4 idx [0,272)=h0@p0, [272,456)=h1@p1, [456,520)=h2@p0
    const float4* hx0 = (const float4*)(p.hx + (size_t)(p0 * GRP + g) * HBLK);
    const float4* hx1 = (const float4*)(p.hx + (size_t)(p1 * GRP + g) * HBLK);
    const int i1 = tid + 256;
    const float4 hv0 = cload(hx0 + tid);   // tid<256 -> always h0 region
    const float4 hv1 = cload((i1 >= 272 && i1 < 456) ? hx1 + i1 : hx0 + i1);
    float4 hvt;
    if (tid < 8) hvt = cload(hx0 + 512 + tid);

    // -- x store (prefetched during previous tick's GEMM) --
    *(float4*)(&smem[xr_r * ZP + xr_c4]) = xr;

    cwait();

    // -- scatter h to LDS (dual stores for shared segments) --
    {
      const int r = tid / 34, c4 = (tid - r * 34) * 4;   // h0 part
      *(float4*)(&smem[r * ZP + 128 + c4]) = hv0;
      *(float4*)(&smem[ZB1s + r * ZP + c4]) = hv0;
    }
    if (i1 < 272) {
      const int r = i1 / 34, c4 = (i1 - r * 34) * 4;
      *(float4*)(&smem[r * ZP + 128 + c4]) = hv1;
      *(float4*)(&smem[ZB1s + r * ZP + c4]) = hv1;
    } else if (i1 < 456) {
      const int j = i1 - 272;
      const int r = j / 23, c4 = (j - r * 23) * 4;
      *(float4*)(&smem[ZB1s + r * ZP + 136 + c4]) = hv1;
      *(float4*)(&smem[ZB2s + r * ZP + c4]) = hv1;
    } else {
      const int j = i1 - 456;
      const int r = j >> 3, c4 = (j & 7) * 4;
      *(float4*)(&smem[ZB2s + r * ZP + 92 + c4]) = hv1;
    }
    if (tid < 8) {
      const int j = tid + 56;                            // f4 idx 512..519
      const int r = j >> 3, c4 = (j & 7) * 4;
      *(float4*)(&smem[ZB2s + r * ZP + 92 + c4]) = hvt;
    }
    __syncthreads();

    // -- coalesced out write: h2(k-3) assembled in z2; WG w owns row w --
    if (tid < 8 && k >= 3) {
      const float4 v = *(const float4*)(&smem[ZB2s + w_idx * ZP + 92 + tid * 4]);
      *(float4*)(&p.out[((size_t)(g * 8 + w_idx) * TT + (k - 3)) * 32 + tid * 4]) = v;
    }

    // -- prefetch next tick's x (overlaps GEMM; consumed next tick) --
    {
      const int txn = (k + 1 < TT) ? (k + 1) : TT - 1;
      xr = *(const float4*)(xbase + (size_t)txn * 128);
    }

    // -- fused GEMM, per-row: 3 mats x 9 f4 chunk reads; symmetric reduce
    //    over K-lanes {b0,b1} via shfl_xor(1)/(2); compile-time extraction.
    float own0 = 0.f, own1 = 0.f, own2 = 0.f;
    float giv0 = 0.f, giv1 = 0.f, giv2 = 0.f;
    {
      const float* zp = &smem[zb + k0];
      #pragma unroll
      for (int r = 0; r < 8; ++r) {
        f2 a0 = {0.f, 0.f}, a1 = {0.f, 0.f}, a2 = {0.f, 0.f};
        #pragma unroll
        for (int i = 0; i < 9; ++i) {
          const float4 z4 = *(const float4*)(zp + r * ZP + i * 4);
          const f2 zl = {z4.x, z4.y}, zh = {z4.z, z4.w};
          a0 = __builtin_elementwise_fma(zl, w0l[i], a0);
          a1 = __builtin_elementwise_fma(zl, w1l[i], a1);
          a2 = __builtin_elementwise_fma(zl, w2l[i], a2);
          a0 = __builtin_elementwise_fma(zh, w0h[i], a0);
          a1 = __builtin_elementwise_fma(zh, w1h[i], a1);
          a2 = __builtin_elementwise_fma(zh, w2h[i], a2);
        }
        float u0 = a0.x + a0.y, u1 = a1.x + a1.y, u2 = a2.x + a2.y;
        u0 += __shfl_xor(u0, 1);  u0 += __shfl_xor(u0, 2);
        u1 += __shfl_xor(u1, 1);  u1 += __shfl_xor(u1, 2);
        u2 += __shfl_xor(u2, 1);  u2 += __shfl_xor(u2, 2);
        if (r == q8)       { own0 = u0; own1 = u1; own2 = u2; }
        if (r == (q8 ^ 4)) { giv0 = u0; giv1 = u1; giv2 = u2; }
      }
    }
    // -- cross-half exchange (b2 subgroups) via LDS scratch: partner tid^4 is
    //    SAME WAVE -> in-wave lgkmcnt ordering suffices (no __syncthreads).
    *(float4*)(&smem[SCR + tid * 4]) = (float4){giv0, giv1, giv2, 0.f};
    asm volatile("s_waitcnt lgkmcnt(0)" ::: "memory");
    __builtin_amdgcn_sched_barrier(0);
    const float4 par = *(const float4*)(&smem[SCR + (tid ^ 4) * 4]);

    const float F1 = own0 + par.x + bf1;
    const float F2 = own1 + par.y + bf2;
    const float T  = own2 + par.z + bt;
    const float t  = frcp(1.f + __expf(-T));
    const float h  = ftanh(F1) * (1.f - t) + t * ftanh(F2);
    const int   tl = k - lyr;
    if (tl >= 0 && tl < TT) {
      float* dst = p.hx + (size_t)((tl & 1) * GRP + g) * HBLK + seg + ug;
      sysstore(dst + (size_t)q8 * UP, h);               // write-through to MALL
    }

    // -- group barrier: per-WG flag store (no RMW) + 8-lane single-line poll --
    __syncthreads();   // all waves drain vmcnt (h stores acked at MALL)
    if (tid == 0)
      __hip_atomic_store(&p.flags[g * 16 + w_idx], k + 1,
                         __ATOMIC_RELAXED, __HIP_MEMORY_SCOPE_SYSTEM);
    if (k < TT + 2) {
      if (tid < WPG) {
        const int* fp = &p.flags[g * 16 + tid];
        while (__hip_atomic_load(fp, __ATOMIC_RELAXED, __HIP_MEMORY_SCOPE_SYSTEM) < k + 1)
          __builtin_amdgcn_s_sleep(1);
      }
      __syncthreads();
    }
  }
}

// in-place fc: out[b,t,:] = out[b,t,:] @ fc_w.T + fc_b  (pool is identity)
extern "C" __global__ void __launch_bounds__(256)
lnn_fc(float* out, const float* fcw, const float* fcb) {
  __shared__ float w[32 * 33];
  __shared__ float bb[32];
  __shared__ float tile[8 * 32];
  const int tid = threadIdx.x;
  for (int i = tid; i < 1024; i += 256) w[(i >> 5) * 33 + (i & 31)] = fcw[i];
  if (tid < 32) bb[tid] = fcb[tid];
  const size_t base = (size_t)blockIdx.x * 256;
  tile[tid] = out[base + tid];
  __syncthreads();
  const int pp = tid >> 5, o = tid & 31;
  float acc = bb[o];
  #pragma unroll
  for (int u = 0; u < 32; ++u) acc = fmaf(tile[pp * 32 + u], w[o * 33 + u], acc);
  out[base + pp * 32 + o] = acc;
}

extern "C" void kernel_launch(void* const* d_in, const int* in_sizes, int n_in,
                              void* d_out, int out_size, void* d_ws, size_t ws_size,
                              hipStream_t stream) {
  Params p;
  p.x = (const float*)d_in[0];
  const int wi[3] = {1, 10, 19};
  for (int l = 0; l < 3; ++l) {
    for (int m = 0; m < 4; ++m) {
      p.w[l][m] = (const float*)d_in[wi[l] + 2 * m];
      p.b[l][m] = (const float*)d_in[wi[l] + 2 * m + 1];
    }
  }
  p.mk[0] = (const int*)d_in[9];
  p.mk[1] = (const int*)d_in[18];
  p.mk[2] = (const int*)d_in[27];
  float* ws = (float*)d_ws;
  p.hx    = ws;
  p.flags = (int*)(ws + FLAG_OFF);
  p.out   = (float*)d_out;

  hipFuncSetAttribute(reinterpret_cast<const void*>(lnn_main),
                      hipFuncAttributeMaxDynamicSharedMemorySize, SMEM_BYTES);
  hipMemsetAsync(d_ws, 0, (size_t)WS_DW * 4, stream);
  lnn_main<<<dim3(GRP * WPG), dim3(256), SMEM_BYTES, stream>>>(p);
  lnn_fc<<<dim3(NB * TT / 8), dim3(256), 0, stream>>>(
      (float*)d_out, (const float*)d_in[28], (const float*)d_in[29]);
}